// Round 1
// baseline (1525.115 us; speedup 1.0000x reference)
//
#include <hip/hip_runtime.h>
#include <hip/hip_bf16.h>

// Fuzzy_Attention_Encoder: B=64,S=4,L=64,D=64,R=64. 16384 rows of 64.
// Round 0: correct fp32 baseline with runtime bf16/fp32 input detection
// (ln_g[0] as u32: fp32 ones = 0x3F800000, bf16 ones-pair = 0x3F803F80).
// Output dtype follows the same flag.
//
// Pipeline: k_fss -> k_attn (attn GEMM via A'[row,(r,d)]=Fss*x, Wc is row-major
// [t,4096] after the '(t r)' reshape; fused h=x+attn + LN-stat atomics) ->
// k_norm -> k_ffn1 (fp32 tiled GEMM, K-split-2, atomic partials) -> k_ffn23.

__device__ __forceinline__ float b2f(unsigned short v){
  union { unsigned u; float f; } c; c.u = ((unsigned)v) << 16; return c.f;
}

template<bool BF>
__device__ __forceinline__ float ldg1(const void* p, int i){
  if constexpr (BF) return b2f(((const unsigned short*)p)[i]);
  else return ((const float*)p)[i];
}

template<bool BF>
__device__ __forceinline__ float4 ldg4(const void* p, int i){  // i % 4 == 0
  if constexpr (BF){
    ushort4 u = *(const ushort4*)(((const unsigned short*)p) + i);
    return make_float4(b2f(u.x), b2f(u.y), b2f(u.z), b2f(u.w));
  } else {
    return *(const float4*)(((const float*)p) + i);
  }
}

__device__ __forceinline__ bool detect_bf16(const void* lng){
  return ((const unsigned*)lng)[0] != 0x3F800000u;
}

// ---------------- kernel 1: q, fuzzy membership z, softmax -> Fss ----------
template<bool BF>
__device__ void fss_body(const void* x, const void* Wq, const void* bq,
                         const void* cen, const void* wid, float* fss){
  __shared__ float xs[64];
  __shared__ float qs[64];
  int t = threadIdx.x;
  int row = blockIdx.x;
  xs[t] = ldg1<BF>(x, row*64 + t);
  __syncthreads();
  float acc = ldg1<BF>(bq, t);
  #pragma unroll
  for (int d4 = 0; d4 < 16; d4++){
    float4 wv = ldg4<BF>(Wq, t*64 + d4*4);
    float4 xv = *(float4*)&xs[d4*4];
    acc += wv.x*xv.x + wv.y*xv.y + wv.z*xv.z + wv.w*xv.w;
  }
  qs[t] = acc;
  __syncthreads();
  float zs = 0.f;
  #pragma unroll
  for (int d4 = 0; d4 < 16; d4++){
    float4 cv = ldg4<BF>(cen, t*64 + d4*4);
    float4 wv = ldg4<BF>(wid, t*64 + d4*4);
    float4 qv = *(float4*)&qs[d4*4];
    float e0 = __fdividef(qv.x - cv.x, wv.x);
    float e1 = __fdividef(qv.y - cv.y, wv.y);
    float e2 = __fdividef(qv.z - cv.z, wv.z);
    float e3 = __fdividef(qv.w - cv.w, wv.w);
    zs += e0*e0 + e1*e1 + e2*e2 + e3*e3;
  }
  float z = zs * (-0.5f / 64.f);
  float m = z;
  #pragma unroll
  for (int off = 32; off; off >>= 1) m = fmaxf(m, __shfl_xor(m, off));
  float e = expf(z - m);
  float s = e;
  #pragma unroll
  for (int off = 32; off; off >>= 1) s += __shfl_xor(s, off);
  fss[row*64 + t] = __fdividef(e, s);
}

__global__ void __launch_bounds__(64)
k_fss(const void* x, const void* Wq, const void* bq, const void* cen,
      const void* wid, const void* lng, float* fss){
  if (detect_bf16(lng)) fss_body<true>(x, Wq, bq, cen, wid, fss);
  else                  fss_body<false>(x, Wq, bq, cen, wid, fss);
}

// ------------- kernel 2: attn GEMM + h = x + attn + LN stat atomics --------
template<bool BF>
__device__ void attn_body(const void* x, const void* Wc, const void* bc,
                          const float* fss, float* h, float* stats){
  __shared__ float lx[64][68];
  __shared__ float lw[64][68];
  __shared__ float lf[64][65];
  __shared__ float sred[8];
  int tid  = threadIdx.x;
  int row0 = blockIdx.x * 64;
  {
    int rl = tid >> 2, seg = tid & 3;
    #pragma unroll
    for (int j4 = 0; j4 < 4; j4++){
      int d = seg*4 + j4*16;
      float4 v = ldg4<BF>(x, (row0+rl)*64 + d);
      *(float4*)&lx[rl][d] = v;
      float4 f = *(const float4*)&fss[(row0+rl)*64 + d];
      lf[rl][d+0] = f.x; lf[rl][d+1] = f.y; lf[rl][d+2] = f.z; lf[rl][d+3] = f.w;
    }
  }
  __syncthreads();
  int tx = tid & 15, ty = tid >> 4;
  int t0 = tx*4, m0 = ty*4;
  float C[4][4];
  #pragma unroll
  for (int i = 0; i < 4; i++)
    #pragma unroll
    for (int j = 0; j < 4; j++) C[i][j] = 0.f;

  int st = tid >> 2, sseg = tid & 3;
  for (int r = 0; r < 64; r++){
    #pragma unroll
    for (int j4 = 0; j4 < 4; j4++){
      int d = sseg*4 + j4*16;
      *(float4*)&lw[st][d] = ldg4<BF>(Wc, st*4096 + r*64 + d);
    }
    __syncthreads();
    float w[4];
    #pragma unroll
    for (int i = 0; i < 4; i++) w[i] = lf[m0+i][r];
    float S[4][4];
    #pragma unroll
    for (int i = 0; i < 4; i++)
      #pragma unroll
      for (int j = 0; j < 4; j++) S[i][j] = 0.f;
    #pragma unroll
    for (int d4 = 0; d4 < 16; d4++){
      float4 a[4], bb[4];
      #pragma unroll
      for (int i = 0; i < 4; i++) a[i]  = *(float4*)&lx[m0+i][d4*4];
      #pragma unroll
      for (int j = 0; j < 4; j++) bb[j] = *(float4*)&lw[t0+j][d4*4];
      #pragma unroll
      for (int i = 0; i < 4; i++)
        #pragma unroll
        for (int j = 0; j < 4; j++)
          S[i][j] += a[i].x*bb[j].x + a[i].y*bb[j].y + a[i].z*bb[j].z + a[i].w*bb[j].w;
    }
    #pragma unroll
    for (int j = 0; j < 4; j++){
      float bcv = ldg1<BF>(bc, (t0+j)*64 + r);
      #pragma unroll
      for (int i = 0; i < 4; i++)
        C[i][j] += w[i] * (S[i][j] + bcv);
    }
    __syncthreads();
  }
  // epilogue: h = x + attn, per-batch sum/sumsq
  float lsum = 0.f, lsq = 0.f;
  #pragma unroll
  for (int i = 0; i < 4; i++){
    float4 hv;
    hv.x = lx[m0+i][t0+0] + C[i][0];
    hv.y = lx[m0+i][t0+1] + C[i][1];
    hv.z = lx[m0+i][t0+2] + C[i][2];
    hv.w = lx[m0+i][t0+3] + C[i][3];
    *(float4*)&h[(row0+m0+i)*64 + t0] = hv;
    lsum += hv.x + hv.y + hv.z + hv.w;
    lsq  += hv.x*hv.x + hv.y*hv.y + hv.z*hv.z + hv.w*hv.w;
  }
  #pragma unroll
  for (int off = 32; off; off >>= 1){
    lsum += __shfl_xor(lsum, off);
    lsq  += __shfl_xor(lsq,  off);
  }
  int lane = tid & 63, wid = tid >> 6;
  if (lane == 0){ sred[wid] = lsum; sred[4+wid] = lsq; }
  __syncthreads();
  if (tid == 0){
    float s  = sred[0] + sred[1] + sred[2] + sred[3];
    float s2 = sred[4] + sred[5] + sred[6] + sred[7];
    int b = blockIdx.x >> 2;
    atomicAdd(&stats[b*2 + 0], s);
    atomicAdd(&stats[b*2 + 1], s2);
  }
}

__global__ void __launch_bounds__(256)
k_attn(const void* x, const void* Wc, const void* bc, const void* lng,
       const float* fss, float* h, float* stats){
  if (detect_bf16(lng)) attn_body<true>(x, Wc, bc, fss, h, stats);
  else                  attn_body<false>(x, Wc, bc, fss, h, stats);
}

// ---------------- kernel 3: LayerNorm normalize ----------------------------
template<bool BF>
__device__ void norm_body(const float* h, const float* stats, const void* g,
                          const void* be, float* hn){
  int gid = blockIdx.x * 256 + threadIdx.x;
  int e0  = gid * 4;
  int b   = e0 >> 14;
  int i   = e0 & 16383;
  float s  = stats[b*2 + 0];
  float s2 = stats[b*2 + 1];
  float mu  = s * (1.f/16384.f);
  float var = s2 * (1.f/16384.f) - mu*mu;
  float rs  = rsqrtf(var + 1e-5f);
  float4 hv = *(const float4*)&h[e0];
  float4 gv = ldg4<BF>(g, i);
  float4 bv = ldg4<BF>(be, i);
  float4 o;
  o.x = (hv.x - mu)*rs*gv.x + bv.x;
  o.y = (hv.y - mu)*rs*gv.y + bv.y;
  o.z = (hv.z - mu)*rs*gv.z + bv.z;
  o.w = (hv.w - mu)*rs*gv.w + bv.w;
  *(float4*)&hn[e0] = o;
}

__global__ void __launch_bounds__(256)
k_norm(const float* h, const float* stats, const void* g, const void* be,
       const void* lng, float* hn){
  if (detect_bf16(lng)) norm_body<true>(h, stats, g, be, hn);
  else                  norm_body<false>(h, stats, g, be, hn);
}

// ---------------- kernel 4: FFN layer 1 (streams W1) -----------------------
template<bool BF>
__device__ void ffn1_body(const float* hn, const void* W1, float* f1){
  __shared__ float la[64][68];
  __shared__ float lb[32][68];
  int tid = threadIdx.x;
  int nt = blockIdx.x >> 1, kh = blockIdx.x & 1;
  int n0 = nt * 32;
  int tx = tid & 15, ty = tid >> 4;
  int nl0 = tx*2, m0 = ty*4;
  float C[4][2];
  #pragma unroll
  for (int i = 0; i < 4; i++){ C[i][0] = 0.f; C[i][1] = 0.f; }
  int rl = tid >> 2, seg = tid & 3;
  int wl = tid >> 3, s8  = tid & 7;
  int kbeg = kh * 8192;
  for (int kc = kbeg; kc < kbeg + 8192; kc += 64){
    #pragma unroll
    for (int j4 = 0; j4 < 4; j4++){
      int d = seg*4 + j4*16;
      *(float4*)&la[rl][d] = *(const float4*)&hn[rl*16384 + kc + d];
    }
    #pragma unroll
    for (int j4 = 0; j4 < 2; j4++){
      int d = s8*4 + j4*32;
      *(float4*)&lb[wl][d] = ldg4<BF>(W1, (n0+wl)*16384 + kc + d);
    }
    __syncthreads();
    #pragma unroll
    for (int d4 = 0; d4 < 16; d4++){
      float4 a[4], bb[2];
      #pragma unroll
      for (int i = 0; i < 4; i++) a[i]  = *(float4*)&la[m0+i][d4*4];
      #pragma unroll
      for (int j = 0; j < 2; j++) bb[j] = *(float4*)&lb[nl0+j][d4*4];
      #pragma unroll
      for (int i = 0; i < 4; i++)
        #pragma unroll
        for (int j = 0; j < 2; j++)
          C[i][j] += a[i].x*bb[j].x + a[i].y*bb[j].y + a[i].z*bb[j].z + a[i].w*bb[j].w;
    }
    __syncthreads();
  }
  #pragma unroll
  for (int i = 0; i < 4; i++)
    #pragma unroll
    for (int j = 0; j < 2; j++)
      atomicAdd(&f1[(m0+i)*8192 + n0 + nl0 + j], C[i][j]);
}

__global__ void __launch_bounds__(256)
k_ffn1(const float* hn, const void* W1, const void* lng, float* f1){
  if (detect_bf16(lng)) ffn1_body<true>(hn, W1, f1);
  else                  ffn1_body<false>(hn, W1, f1);
}

// ---------------- kernel 5: FFN layers 2+3 ---------------------------------
template<bool BF>
__device__ void ffn23_body(const float* f1, const void* b1, const void* W2,
                           const void* b2, const void* W3, const void* b3,
                           void* out){
  __shared__ float sf[8192];
  __shared__ float p[4][64];
  __shared__ float sf2[64];
  int m = blockIdx.x, tid = threadIdx.x;
  #pragma unroll
  for (int j4 = 0; j4 < 8; j4++){
    int k = tid*4 + j4*1024;
    float4 v  = *(const float4*)&f1[m*8192 + k];
    float4 bb = ldg4<BF>(b1, k);
    sf[k+0] = fmaxf(v.x + bb.x, 0.f);
    sf[k+1] = fmaxf(v.y + bb.y, 0.f);
    sf[k+2] = fmaxf(v.z + bb.z, 0.f);
    sf[k+3] = fmaxf(v.w + bb.w, 0.f);
  }
  __syncthreads();
  int n = tid & 63, kq = tid >> 6;
  float acc = 0.f;
  for (int k = kq*2048; k < kq*2048 + 2048; k += 4){
    float4 wv = ldg4<BF>(W2, n*8192 + k);
    float4 sv = *(const float4*)&sf[k];
    acc += wv.x*sv.x + wv.y*sv.y + wv.z*sv.z + wv.w*sv.w;
  }
  p[kq][n] = acc;
  __syncthreads();
  if (tid < 64){
    float t = p[0][tid] + p[1][tid] + p[2][tid] + p[3][tid] + ldg1<BF>(b2, tid);
    sf2[tid] = fmaxf(t, 0.f);
  }
  __syncthreads();
  if (tid < 2){
    float acc2 = ldg1<BF>(b3, tid);
    for (int nn = 0; nn < 64; nn++)
      acc2 += sf2[nn] * ldg1<BF>(W3, tid*64 + nn);
    if constexpr (BF) ((__hip_bfloat16*)out)[m*2 + tid] = __float2bfloat16(acc2);
    else              ((float*)out)[m*2 + tid] = acc2;
  }
}

__global__ void __launch_bounds__(256)
k_ffn23(const float* f1, const void* b1, const void* W2, const void* b2,
        const void* W3, const void* b3, const void* lng, void* out){
  if (detect_bf16(lng)) ffn23_body<true>(f1, b1, W2, b2, W3, b3, out);
  else                  ffn23_body<false>(f1, b1, W2, b2, W3, b3, out);
}

// ---------------------------------------------------------------------------
extern "C" void kernel_launch(void* const* d_in, const int* in_sizes, int n_in,
                              void* d_out, int out_size, void* d_ws, size_t ws_size,
                              hipStream_t stream){
  const void* x       = d_in[0];
  const void* Wq      = d_in[1];
  const void* bq      = d_in[2];
  const void* centers = d_in[3];
  const void* widths  = d_in[4];
  const void* Wc      = d_in[5];
  const void* bc      = d_in[6];
  const void* ln_g    = d_in[7];
  const void* ln_b    = d_in[8];
  const void* W1      = d_in[9];
  const void* b1      = d_in[10];
  const void* W2      = d_in[11];
  const void* b2      = d_in[12];
  const void* W3      = d_in[13];
  const void* b3      = d_in[14];

  float* ws    = (float*)d_ws;
  float* fss   = ws + 0;        // 16384*64 = 1,048,576 floats
  float* h     = ws + 1048576;  // 1,048,576
  float* hn    = ws + 2097152;  // 1,048,576
  float* f1    = ws + 3145728;  //   524,288
  float* stats = ws + 3670016;  //       128  (contiguous after f1)

  hipMemsetAsync(f1, 0, (524288 + 128) * sizeof(float), stream);
  k_fss  <<<16384,  64, 0, stream>>>(x, Wq, bq, centers, widths, ln_g, fss);
  k_attn <<<  256, 256, 0, stream>>>(x, Wc, bc, ln_g, fss, h, stats);
  k_norm <<< 1024, 256, 0, stream>>>(h, stats, ln_g, ln_b, ln_g, hn);
  k_ffn1 <<<  512, 256, 0, stream>>>(hn, W1, ln_g, f1);
  k_ffn23<<<   64, 256, 0, stream>>>(f1, b1, W2, b2, W3, b3, ln_g, d_out);
}